// Round 4
// baseline (241.115 us; speedup 1.0000x reference)
//
#include <hip/hip_runtime.h>
#include <math.h>

#define BB 64
#define FF 256
#define CC 100000
#define PMARG 0.2f
#define NMARG 0.3f
#define CPB 128                  // cols per gemm block
#define GBLK 782                 // ceil(CC/CPB); block GBLK = Gram
#define WS_GRAM_OFF 64           // ws: [0..63] row exp-sums | [64..] Gram 64x64

typedef __attribute__((ext_vector_type(8))) short short8;   // 8 bf16
typedef __attribute__((ext_vector_type(4))) short sh4;      // 4 bf16 = 8B
typedef __attribute__((ext_vector_type(4))) float f32x4;

__device__ __forceinline__ float wredf(float v) {
#pragma unroll
    for (int s = 1; s < 64; s <<= 1) v += __shfl_xor(v, s, 64);
    return v;
}

// f32 -> bf16 round-to-nearest-even
__device__ __forceinline__ short f2bf(float f) {
    unsigned u = __float_as_uint(f);
    unsigned r = (u + 0x7fffu + ((u >> 16) & 1u)) >> 16;
    return (short)r;
}
__device__ __forceinline__ short8 pack8(float4 a, float4 b) {
    short8 o;
    o[0] = f2bf(a.x); o[1] = f2bf(a.y); o[2] = f2bf(a.z); o[3] = f2bf(a.w);
    o[4] = f2bf(b.x); o[5] = f2bf(b.y); o[6] = f2bf(b.z); o[7] = f2bf(b.w);
    return o;
}

// blocks 0..GBLK-1: 128 cols each. V tile staged coalesced into LDS as bf16
// (XOR-swizzled). Per wave: 32 cols x 64 rows via mfma_f32_16x16x32_bf16,
// A fragments in VGPRs (64KB A stays L2-resident).
// block GBLK: Gram matrix G = inputs @ inputs.T -> ws[WS_GRAM_OFF..] (f32).
__global__ __launch_bounds__(256, 2) void k_gemm(const float* __restrict__ in,
                                                 const float* __restrict__ V,
                                                 float* __restrict__ logits,
                                                 float* __restrict__ ws) {
    __shared__ char sV[CPB * 512];   // [128 rows][256 cols] bf16, swizzled
    int tid = threadIdx.x;
    const float4* __restrict__ in4 = (const float4*)in;

    if (blockIdx.x == GBLK) {
        // ---- Gram block: 4x4 register tile per thread, f32 for accuracy ----
        int r0 = (tid >> 4) << 2;
        int c0 = (tid & 15) << 2;
        float gacc[4][4];
#pragma unroll
        for (int r = 0; r < 4; ++r)
#pragma unroll
            for (int c = 0; c < 4; ++c) gacc[r][c] = 0.f;
        for (int kq = 0; kq < 64; ++kq) {
            float4 a[4], b[4];
#pragma unroll
            for (int r = 0; r < 4; ++r) a[r] = in4[(r0 + r) * 64 + kq];
#pragma unroll
            for (int c = 0; c < 4; ++c) b[c] = in4[(c0 + c) * 64 + kq];
#pragma unroll
            for (int r = 0; r < 4; ++r)
#pragma unroll
                for (int c = 0; c < 4; ++c)
                    gacc[r][c] += a[r].x * b[c].x + a[r].y * b[c].y +
                                  a[r].z * b[c].z + a[r].w * b[c].w;
        }
        float* G = ws + WS_GRAM_OFF;
#pragma unroll
        for (int r = 0; r < 4; ++r)
#pragma unroll
            for (int c = 0; c < 4; ++c)
                G[(r0 + r) * 64 + (c0 + c)] = gacc[r][c];
        return;
    }

    int col0 = blockIdx.x * CPB;

    // ---- stage V tile: fully coalesced (each wave-load = one 1KB V row) ----
    const float4* __restrict__ V4 = (const float4*)V;
#pragma unroll
    for (int i = 0; i < 32; ++i) {
        int flat = i * 256 + tid;
        int row = flat >> 6;          // 0..127 (tile row = V row col0+row)
        int c8 = flat & 63;           // float4 index within row
        int vr = col0 + row;
        if (vr >= CC) vr = CC - 1;    // pad rows duplicate last (stores guarded)
        float4 gv = V4[(size_t)vr * 64 + c8];
        sh4 b;
        b[0] = f2bf(gv.x); b[1] = f2bf(gv.y); b[2] = f2bf(gv.z); b[3] = f2bf(gv.w);
        int off = (row * 512 + c8 * 8) ^ ((row & 7) << 4);
        *(sh4*)(sV + off) = b;
    }

    int lane = tid & 63, w = tid >> 6;
    int g = lane >> 4, c4 = lane & 15;

    // ---- A fragments: row = lane&15, k = (lane>>4)*8 + j (verified R3) ----
    short8 afrag[4][8];               // 4 m-tiles x 8 k-steps, 128 VGPR
#pragma unroll
    for (int mt = 0; mt < 4; ++mt)
#pragma unroll
        for (int ks = 0; ks < 8; ++ks) {
            int base = (mt * 16 + c4) * 64 + ks * 8 + g * 2;
            afrag[mt][ks] = pack8(in4[base], in4[base + 1]);
        }
    __syncthreads();

    f32x4 acc[4][2];
#pragma unroll
    for (int mt = 0; mt < 4; ++mt)
#pragma unroll
        for (int nt = 0; nt < 2; ++nt) acc[mt][nt] = (f32x4){0.f, 0.f, 0.f, 0.f};

#pragma unroll
    for (int ks = 0; ks < 8; ++ks) {
        short8 bf[2];
#pragma unroll
        for (int nt = 0; nt < 2; ++nt) {
            int rowb = w * 32 + nt * 16 + c4;   // B col index (V row in tile)
            int off = (rowb * 512 + ks * 64 + g * 16) ^ ((rowb & 7) << 4);
            bf[nt] = *(const short8*)(sV + off);
        }
#pragma unroll
        for (int mt = 0; mt < 4; ++mt)
#pragma unroll
            for (int nt = 0; nt < 2; ++nt)
                acc[mt][nt] = __builtin_amdgcn_mfma_f32_16x16x32_bf16(
                    afrag[mt][ks], bf[nt], acc[mt][nt], 0, 0, 0);
    }

    // ---- stores: both 16-col halves back-to-back -> full 128B lines ----
#pragma unroll
    for (int mt = 0; mt < 4; ++mt)
#pragma unroll
        for (int r = 0; r < 4; ++r) {
            int row = mt * 16 + g * 4 + r;
#pragma unroll
            for (int nt = 0; nt < 2; ++nt) {
                int col = col0 + w * 32 + nt * 16 + c4;
                if (col < CC) logits[(size_t)row * CC + col] = acc[mt][nt][r];
            }
        }
}

// 64 blocks, one per batch row: sum exp(logits[row][:]) (logits L2/L3-hot)
__global__ __launch_bounds__(256) void k_rowsum(const float* __restrict__ logits,
                                                float* __restrict__ ws) {
    __shared__ float sS[256];
    int tid = threadIdx.x;
    int row = blockIdx.x;
    const float* __restrict__ lp = logits + (size_t)row * CC;
    float s = 0.f;
    for (int c = tid; c < CC; c += 256) s += expf(lp[c]);   // |logit|<~19, safe
    sS[tid] = s;
    __syncthreads();
    if (tid < 64) {
        float t = sS[tid] + sS[tid + 64] + sS[tid + 128] + sS[tid + 192];
        t = wredf(t);
        if (tid == 0) ws[row] = t;
    }
}

__device__ __forceinline__ bool mask_at(const void* p, int idx, int mode) {
    if (mode == 0) return ((const int*)p)[idx] != 0;
    if (mode == 1) return ((const float*)p)[idx] != 0.f;
    return ((const unsigned char*)p)[idx] != 0;
}

// one wave: bu_loss from rowsums, sims from Gram, hp/hn losses, final scalar
__global__ __launch_bounds__(64) void k_final(const int* __restrict__ targets,
                                              const void* __restrict__ pmask,
                                              const void* __restrict__ nmask,
                                              const float* __restrict__ logits,
                                              const float* __restrict__ ws,
                                              float* __restrict__ out) {
    int lane = threadIdx.x;   // 0..63 == batch row

    // detect mask storage layout: int32 (0/1 words), float32 (0/1.0f), or uint8
    const unsigned int* pw = (const unsigned int*)pmask;
    int okInt = 1, okFlt = 1;
#pragma unroll
    for (int i = 0; i < 16; ++i) {
        unsigned int wv = pw[lane * 16 + i];
        okInt = okInt && (wv <= 1u);
        okFlt = okFlt && (wv == 0u || wv == 0x3f800000u);
    }
    int mode = __all(okInt) ? 0 : (__all(okFlt) ? 1 : 2);

    float lse = logf(ws[lane]);
    int tgt = targets[lane];
    float nll = lse - logits[(size_t)lane * CC + tgt];

    const float* G = ws + WS_GRAM_OFF;
    float rinv = rsqrtf(G[lane * 64 + lane]);

    float minp = INFINITY, maxthd = -INFINITY;
    for (int j = 0; j < 64; ++j) {
        float rj = __shfl(rinv, j, 64);
        float sim = G[lane * 64 + j] * rinv * rj;
        sim = fminf(1.f, fmaxf(-1.f, sim));
        if (j != lane) {
            bool pm = mask_at(pmask, lane * 64 + j, mode);
            float ps = pm ? sim : 2.0f;
            minp = fminf(minp, ps);
            maxthd = fmaxf(maxthd, pm ? sim : -2.0f);   // sentinel 2.0 -> -2.0
        }
    }
    float n_thrd = minp - NMARG;
    float p_thrd = maxthd - PMARG;

    float hps = 0.f, hns = 0.f, hpc = 0.f, hnc = 0.f;
    for (int j = 0; j < 64; ++j) {
        float rj = __shfl(rinv, j, 64);
        float sim = G[lane * 64 + j] * rinv * rj;
        sim = fminf(1.f, fmaxf(-1.f, sim));
        if (j != lane) {
            bool pm = mask_at(pmask, lane * 64 + j, mode);
            bool nm = mask_at(nmask, lane * 64 + j, mode);
            float ps = pm ? sim : 2.0f;
            float ns = nm ? sim : 2.0f;
            if (ps < p_thrd) { hps += log1pf(expf(-ps)); hpc += 1.f; }
            if (ns < n_thrd) { hns += log1pf(expf(-ns)); hnc += 1.f; }
        }
    }

    float snll = wredf(nll);
    float shps = wredf(hps);
    float shns = wredf(hns);
    float shpc = wredf(hpc);
    float shnc = wredf(hnc);
    if (lane == 0) {
        float bu = snll * (1.f / 64.f);
        float hp = shpc > 0.f ? shps / shpc : 0.f;
        float hn = shnc > 0.f ? shns / shnc : 0.f;
        out[0] = bu + hp + hn;
    }
}

extern "C" void kernel_launch(void* const* d_in, const int* in_sizes, int n_in,
                              void* d_out, int out_size, void* d_ws, size_t ws_size,
                              hipStream_t stream) {
    const float* inputs = (const float*)d_in[0];
    const int* targets  = (const int*)d_in[1];
    const void* pmask   = d_in[2];
    const void* nmask   = d_in[3];
    const float* V      = (const float*)d_in[4];
    float* out = (float*)d_out;      // out[0] = loss
    float* logits = out + 1;         // out[1..] = logits [64][100000] row-major
    float* ws = (float*)d_ws;        // [64] rowsums | [64*64] Gram

    hipLaunchKernelGGL(k_gemm, dim3(GBLK + 1), dim3(256), 0, stream,
                       inputs, V, logits, ws);
    hipLaunchKernelGGL(k_rowsum, dim3(64), dim3(256), 0, stream, logits, ws);
    hipLaunchKernelGGL(k_final, dim3(1), dim3(64), 0, stream,
                       targets, pmask, nmask, logits, ws, out);
}

// Round 5
// 171.104 us; speedup vs baseline: 1.4092x; 1.4092x over previous
//
#include <hip/hip_runtime.h>
#include <math.h>

#define BB 64
#define FF 256
#define CC 100000
#define PMARG 0.2f
#define NMARG 0.3f
#define CPB 128                  // cols per gemm block
#define GBLK 782                 // ceil(CC/CPB); block GBLK = Gram
#define WS_GRAM_OFF (GBLK * 64)  // ws: [0..GBLK*64) exp partials | Gram 64x64

typedef __attribute__((ext_vector_type(8))) short short8;   // 8 bf16
typedef __attribute__((ext_vector_type(4))) short sh4;      // 4 bf16 = 8B
typedef __attribute__((ext_vector_type(4))) float f32x4;

__device__ __forceinline__ float wredf(float v) {
#pragma unroll
    for (int s = 1; s < 64; s <<= 1) v += __shfl_xor(v, s, 64);
    return v;
}

// f32 -> bf16 round-to-nearest-even
__device__ __forceinline__ short f2bf(float f) {
    unsigned u = __float_as_uint(f);
    unsigned r = (u + 0x7fffu + ((u >> 16) & 1u)) >> 16;
    return (short)r;
}
__device__ __forceinline__ short8 pack8(float4 a, float4 b) {
    short8 o;
    o[0] = f2bf(a.x); o[1] = f2bf(a.y); o[2] = f2bf(a.z); o[3] = f2bf(a.w);
    o[4] = f2bf(b.x); o[5] = f2bf(b.y); o[6] = f2bf(b.z); o[7] = f2bf(b.w);
    return o;
}

// blocks 0..GBLK-1: 128 cols each. V tile staged coalesced into LDS as bf16
// (XOR-swizzled). Per wave: 32 cols x 64 rows via mfma_f32_16x16x32_bf16.
// Fused epilogue: per-block exp row-sums -> ws (deterministic partials).
// block GBLK: Gram matrix G = inputs @ inputs.T -> ws[WS_GRAM_OFF..] (f32).
__global__ __launch_bounds__(256, 2) void k_gemm(const float* __restrict__ in,
                                                 const float* __restrict__ V,
                                                 float* __restrict__ logits,
                                                 float* __restrict__ ws) {
    __shared__ char sV[CPB * 512];   // [128 rows][256 cols] bf16, swizzled
    __shared__ float sW[4 * 64];
    int tid = threadIdx.x;
    const float4* __restrict__ in4 = (const float4*)in;

    if (blockIdx.x == GBLK) {
        // ---- Gram block: 4x4 register tile per thread, f32 for accuracy ----
        int r0 = (tid >> 4) << 2;
        int c0 = (tid & 15) << 2;
        float gacc[4][4];
#pragma unroll
        for (int r = 0; r < 4; ++r)
#pragma unroll
            for (int c = 0; c < 4; ++c) gacc[r][c] = 0.f;
        for (int kq = 0; kq < 64; ++kq) {
            float4 a[4], b[4];
#pragma unroll
            for (int r = 0; r < 4; ++r) a[r] = in4[(r0 + r) * 64 + kq];
#pragma unroll
            for (int c = 0; c < 4; ++c) b[c] = in4[(c0 + c) * 64 + kq];
#pragma unroll
            for (int r = 0; r < 4; ++r)
#pragma unroll
                for (int c = 0; c < 4; ++c)
                    gacc[r][c] += a[r].x * b[c].x + a[r].y * b[c].y +
                                  a[r].z * b[c].z + a[r].w * b[c].w;
        }
        float* G = ws + WS_GRAM_OFF;
#pragma unroll
        for (int r = 0; r < 4; ++r)
#pragma unroll
            for (int c = 0; c < 4; ++c)
                G[(r0 + r) * 64 + (c0 + c)] = gacc[r][c];
        return;
    }

    int col0 = blockIdx.x * CPB;

    // ---- stage V tile: fully coalesced (each wave-load = one 1KB V row) ----
    const float4* __restrict__ V4 = (const float4*)V;
#pragma unroll
    for (int i = 0; i < 32; ++i) {
        int flat = i * 256 + tid;
        int row = flat >> 6;          // 0..127 (tile row = V row col0+row)
        int c8 = flat & 63;           // float4 index within row
        int vr = col0 + row;
        if (vr >= CC) vr = CC - 1;    // pad rows duplicate last (guarded later)
        float4 gv = V4[(size_t)vr * 64 + c8];
        sh4 b;
        b[0] = f2bf(gv.x); b[1] = f2bf(gv.y); b[2] = f2bf(gv.z); b[3] = f2bf(gv.w);
        int off = (row * 512 + c8 * 8) ^ ((row & 7) << 4);
        *(sh4*)(sV + off) = b;
    }

    int lane = tid & 63, w = tid >> 6;
    int g = lane >> 4, c4 = lane & 15;

    // ---- A fragments: row = lane&15, k = (lane>>4)*8 + j ----
    short8 afrag[4][8];               // 4 m-tiles x 8 k-steps, 128 VGPR
#pragma unroll
    for (int mt = 0; mt < 4; ++mt)
#pragma unroll
        for (int ks = 0; ks < 8; ++ks) {
            int base = (mt * 16 + c4) * 64 + ks * 8 + g * 2;
            afrag[mt][ks] = pack8(in4[base], in4[base + 1]);
        }
    __syncthreads();

    f32x4 acc[4][2];
#pragma unroll
    for (int mt = 0; mt < 4; ++mt)
#pragma unroll
        for (int nt = 0; nt < 2; ++nt) acc[mt][nt] = (f32x4){0.f, 0.f, 0.f, 0.f};

#pragma unroll
    for (int ks = 0; ks < 8; ++ks) {
        short8 bf[2];
#pragma unroll
        for (int nt = 0; nt < 2; ++nt) {
            int rowb = w * 32 + nt * 16 + c4;   // B col index (V row in tile)
            int off = (rowb * 512 + ks * 64 + g * 16) ^ ((rowb & 7) << 4);
            bf[nt] = *(const short8*)(sV + off);
        }
#pragma unroll
        for (int mt = 0; mt < 4; ++mt)
#pragma unroll
            for (int nt = 0; nt < 2; ++nt)
                acc[mt][nt] = __builtin_amdgcn_mfma_f32_16x16x32_bf16(
                    afrag[mt][ks], bf[nt], acc[mt][nt], 0, 0, 0);
    }

    // ---- stores (full 128B lines per wave) + fused exp row-sum partials ----
    float sums[4][4];
#pragma unroll
    for (int mt = 0; mt < 4; ++mt)
#pragma unroll
        for (int r = 0; r < 4; ++r) sums[mt][r] = 0.f;
#pragma unroll
    for (int mt = 0; mt < 4; ++mt)
#pragma unroll
        for (int r = 0; r < 4; ++r) {
            int row = mt * 16 + g * 4 + r;
#pragma unroll
            for (int nt = 0; nt < 2; ++nt) {
                int col = col0 + w * 32 + nt * 16 + c4;
                bool cv = col < CC;
                float lg = acc[mt][nt][r];
                if (cv) logits[(size_t)row * CC + col] = lg;
                sums[mt][r] += cv ? expf(lg) : 0.f;   // |logit| small, no ovf
            }
        }
    // reduce across the 16 cols held by the 16-lane group
#pragma unroll
    for (int mt = 0; mt < 4; ++mt)
#pragma unroll
        for (int r = 0; r < 4; ++r) {
            float s = sums[mt][r];
            s += __shfl_xor(s, 1, 64);
            s += __shfl_xor(s, 2, 64);
            s += __shfl_xor(s, 4, 64);
            s += __shfl_xor(s, 8, 64);
            if (c4 == 0) sW[w * 64 + mt * 16 + g * 4 + r] = s;
        }
    __syncthreads();
    if (tid < 64) {
        float t = sW[tid] + sW[64 + tid] + sW[128 + tid] + sW[192 + tid];
        ws[(size_t)blockIdx.x * 64 + tid] = t;   // deterministic, no atomics
    }
}

__device__ __forceinline__ bool mask_at(const void* p, int idx, int mode) {
    if (mode == 0) return ((const int*)p)[idx] != 0;
    if (mode == 1) return ((const float*)p)[idx] != 0.f;
    return ((const unsigned char*)p)[idx] != 0;
}

// 256 threads: parallel logsumexp partial combine, wave 0 does scalar tail
__global__ __launch_bounds__(256) void k_final(const int* __restrict__ targets,
                                               const void* __restrict__ pmask,
                                               const void* __restrict__ nmask,
                                               const float* __restrict__ logits,
                                               const float* __restrict__ ws,
                                               float* __restrict__ out) {
    __shared__ float sSe[256];
    int tid = threadIdx.x;
    {
        int row = tid & 63, part = tid >> 6;
        float se = 0.f;
        for (int b = part; b < GBLK; b += 4) se += ws[b * 64 + row];  // coalesced
        sSe[tid] = se;
    }
    __syncthreads();
    if (tid >= 64) return;

    int lane = tid;   // 0..63 == batch row
    float se = sSe[lane] + sSe[64 + lane] + sSe[128 + lane] + sSe[192 + lane];

    // detect mask storage layout: int32 (0/1 words), float32 (0/1.0f), or uint8
    const unsigned int* pw = (const unsigned int*)pmask;
    int okInt = 1, okFlt = 1;
#pragma unroll
    for (int i = 0; i < 16; ++i) {
        unsigned int wv = pw[lane * 16 + i];
        okInt = okInt && (wv <= 1u);
        okFlt = okFlt && (wv == 0u || wv == 0x3f800000u);
    }
    int mode = __all(okInt) ? 0 : (__all(okFlt) ? 1 : 2);

    float lse = logf(se);
    int tgt = targets[lane];
    float nll = lse - logits[(size_t)lane * CC + tgt];

    const float* G = ws + WS_GRAM_OFF;
    float rinv = rsqrtf(G[lane * 64 + lane]);

    float minp = INFINITY, maxthd = -INFINITY;
    for (int j = 0; j < 64; ++j) {
        float rj = __shfl(rinv, j, 64);
        float sim = G[lane * 64 + j] * rinv * rj;
        sim = fminf(1.f, fmaxf(-1.f, sim));
        if (j != lane) {
            bool pm = mask_at(pmask, lane * 64 + j, mode);
            float ps = pm ? sim : 2.0f;
            minp = fminf(minp, ps);
            maxthd = fmaxf(maxthd, pm ? sim : -2.0f);   // sentinel 2.0 -> -2.0
        }
    }
    float n_thrd = minp - NMARG;
    float p_thrd = maxthd - PMARG;

    float hps = 0.f, hns = 0.f, hpc = 0.f, hnc = 0.f;
    for (int j = 0; j < 64; ++j) {
        float rj = __shfl(rinv, j, 64);
        float sim = G[lane * 64 + j] * rinv * rj;
        sim = fminf(1.f, fmaxf(-1.f, sim));
        if (j != lane) {
            bool pm = mask_at(pmask, lane * 64 + j, mode);
            bool nm = mask_at(nmask, lane * 64 + j, mode);
            float ps = pm ? sim : 2.0f;
            float ns = nm ? sim : 2.0f;
            if (ps < p_thrd) { hps += log1pf(expf(-ps)); hpc += 1.f; }
            if (ns < n_thrd) { hns += log1pf(expf(-ns)); hnc += 1.f; }
        }
    }

    float snll = wredf(nll);
    float shps = wredf(hps);
    float shns = wredf(hns);
    float shpc = wredf(hpc);
    float shnc = wredf(hnc);
    if (lane == 0) {
        float bu = snll * (1.f / 64.f);
        float hp = shpc > 0.f ? shps / shpc : 0.f;
        float hn = shnc > 0.f ? shns / shnc : 0.f;
        out[0] = bu + hp + hn;
    }
}

extern "C" void kernel_launch(void* const* d_in, const int* in_sizes, int n_in,
                              void* d_out, int out_size, void* d_ws, size_t ws_size,
                              hipStream_t stream) {
    const float* inputs = (const float*)d_in[0];
    const int* targets  = (const int*)d_in[1];
    const void* pmask   = d_in[2];
    const void* nmask   = d_in[3];
    const float* V      = (const float*)d_in[4];
    float* out = (float*)d_out;      // out[0] = loss
    float* logits = out + 1;         // out[1..] = logits [64][100000] row-major
    float* ws = (float*)d_ws;        // [GBLK*64] exp partials | [64*64] Gram

    hipLaunchKernelGGL(k_gemm, dim3(GBLK + 1), dim3(256), 0, stream,
                       inputs, V, logits, ws);
    hipLaunchKernelGGL(k_final, dim3(1), dim3(256), 0, stream,
                       targets, pmask, nmask, logits, ws, out);
}

// Round 6
// 141.004 us; speedup vs baseline: 1.7100x; 1.2135x over previous
//
#include <hip/hip_runtime.h>
#include <math.h>

#define BB 64
#define FF 256
#define CC 100000
#define PMARG 0.2f
#define NMARG 0.3f
#define CGB 64                   // cols per gemm block (8 waves x 16 cols.. 4 groups x 2 row-halves)
#define NGB 1563                 // ceil(CC/CGB)
#define WS_A_OFF 0               // ws: [0..8191] A bf16 fragment pack (32KB)
#define WS_GRAM_OFF 8192         // [8192..12287] Gram 64x64 f32
#define WS_PART_OFF 12288        // [12288..] exp partials NGB*64

typedef __attribute__((ext_vector_type(8))) short short8;   // 8 bf16 = 4 VGPR
typedef __attribute__((ext_vector_type(4))) float f32x4;

__device__ __forceinline__ float wredf(float v) {
#pragma unroll
    for (int s = 1; s < 64; s <<= 1) v += __shfl_xor(v, s, 64);
    return v;
}

// f32 -> bf16 round-to-nearest-even
__device__ __forceinline__ short f2bf(float f) {
    unsigned u = __float_as_uint(f);
    unsigned r = (u + 0x7fffu + ((u >> 16) & 1u)) >> 16;
    return (short)r;
}
__device__ __forceinline__ short8 pack8(float4 a, float4 b) {
    short8 o;
    o[0] = f2bf(a.x); o[1] = f2bf(a.y); o[2] = f2bf(a.z); o[3] = f2bf(a.w);
    o[4] = f2bf(b.x); o[5] = f2bf(b.y); o[6] = f2bf(b.z); o[7] = f2bf(b.w);
    return o;
}

// block 0: pack A into bf16 MFMA fragments (lane-ordered, coalesced for gemm)
// block 1: Gram matrix G = inputs @ inputs.T (f32, accuracy-critical)
__global__ __launch_bounds__(256) void k_prep(const float* __restrict__ in,
                                              float* __restrict__ ws) {
    int tid = threadIdx.x;
    const float4* __restrict__ in4 = (const float4*)in;
    if (blockIdx.x == 0) {
        short8* __restrict__ wsa = (short8*)(ws + WS_A_OFF);
#pragma unroll
        for (int i = 0; i < 8; ++i) {
            int idx = i * 256 + tid;          // (mt*8+ks)*64 + lane
            int lane = idx & 63;
            int ks = (idx >> 6) & 7;
            int mt = idx >> 9;
            int row = mt * 16 + (lane & 15);
            int kq = ks * 8 + (lane >> 4) * 2;   // float4 index
            wsa[idx] = pack8(in4[row * 64 + kq], in4[row * 64 + kq + 1]);
        }
    } else {
        int r0 = (tid >> 4) << 2;
        int c0 = (tid & 15) << 2;
        float gacc[4][4];
#pragma unroll
        for (int r = 0; r < 4; ++r)
#pragma unroll
            for (int c = 0; c < 4; ++c) gacc[r][c] = 0.f;
        for (int kq = 0; kq < 64; ++kq) {
            float4 a[4], b[4];
#pragma unroll
            for (int r = 0; r < 4; ++r) a[r] = in4[(r0 + r) * 64 + kq];
#pragma unroll
            for (int c = 0; c < 4; ++c) b[c] = in4[(c0 + c) * 64 + kq];
#pragma unroll
            for (int r = 0; r < 4; ++r)
#pragma unroll
                for (int c = 0; c < 4; ++c)
                    gacc[r][c] += a[r].x * b[c].x + a[r].y * b[c].y +
                                  a[r].z * b[c].z + a[r].w * b[c].w;
        }
        float* G = ws + WS_GRAM_OFF;
#pragma unroll
        for (int r = 0; r < 4; ++r)
#pragma unroll
            for (int c = 0; c < 4; ++c)
                G[(r0 + r) * 64 + (c0 + c)] = gacc[r][c];
    }
}

// Wave-autonomous GEMM: 8 waves/block, wave = 16 cols x 32 rows.
// All 16 B loads issued up-front (V L3-resident, 64B sectors fully used);
// A fragments are pre-packed bf16 (L2-hot coalesced loads, zero conversion).
// No LDS/barrier until the tiny exp-partial reduce at the end.
__global__ __launch_bounds__(512, 3) void k_gemm(const float* __restrict__ V,
                                                 const float* __restrict__ ws_in,
                                                 float* __restrict__ logits,
                                                 float* __restrict__ ws) {
    __shared__ float sW[64][4];
    int tid = threadIdx.x;
    int lane = tid & 63, w = tid >> 6;
    int cg = w & 3, h = w >> 2;          // col-group 0..3, row-half 0..1
    int g = lane >> 4, c4 = lane & 15;
    int col = blockIdx.x * CGB + cg * 16 + c4;
    bool cv = col < CC;
    int ccol = cv ? col : CC - 1;

    // ---- issue all 16 B loads (f32, 32B per lane per ks) ----
    const float4* __restrict__ vp = (const float4*)(V + (size_t)ccol * FF);
    float4 vb[8][2];
#pragma unroll
    for (int ks = 0; ks < 8; ++ks) {
        vb[ks][0] = vp[ks * 8 + g * 2];
        vb[ks][1] = vp[ks * 8 + g * 2 + 1];
    }

    // ---- A fragments: pre-packed, coalesced, L2-hot ----
    const short8* __restrict__ wsa = (const short8*)(ws_in + WS_A_OFF);
    const short8* __restrict__ ap0 = wsa + (h * 2 + 0) * 512 + lane;
    const short8* __restrict__ ap1 = wsa + (h * 2 + 1) * 512 + lane;

    f32x4 acc0 = {0.f, 0.f, 0.f, 0.f};
    f32x4 acc1 = {0.f, 0.f, 0.f, 0.f};
#pragma unroll
    for (int ks = 0; ks < 8; ++ks) {
        short8 a0 = ap0[ks * 64];
        short8 a1 = ap1[ks * 64];
        short8 bf = pack8(vb[ks][0], vb[ks][1]);
        acc0 = __builtin_amdgcn_mfma_f32_16x16x32_bf16(a0, bf, acc0, 0, 0, 0);
        acc1 = __builtin_amdgcn_mfma_f32_16x16x32_bf16(a1, bf, acc1, 0, 0, 0);
    }

    // ---- epilogue: stores + fused exp partials ----
    // C/D layout: col = lane&15, row = mt*16 + g*4 + r
#pragma unroll
    for (int r = 0; r < 4; ++r) {
        int row0 = (h * 2) * 16 + g * 4 + r;
        int row1 = (h * 2 + 1) * 16 + g * 4 + r;
        float lg0 = acc0[r], lg1 = acc1[r];
        if (cv) {
            logits[(size_t)row0 * CC + col] = lg0;
            logits[(size_t)row1 * CC + col] = lg1;
        }
        float e0 = cv ? expf(lg0) : 0.f;
        float e1 = cv ? expf(lg1) : 0.f;
        e0 += __shfl_xor(e0, 1, 64); e0 += __shfl_xor(e0, 2, 64);
        e0 += __shfl_xor(e0, 4, 64); e0 += __shfl_xor(e0, 8, 64);
        e1 += __shfl_xor(e1, 1, 64); e1 += __shfl_xor(e1, 2, 64);
        e1 += __shfl_xor(e1, 4, 64); e1 += __shfl_xor(e1, 8, 64);
        if (c4 == 0) {
            sW[row0][cg] = e0;
            sW[row1][cg] = e1;
        }
    }
    __syncthreads();
    if (tid < 64) {
        float t = sW[tid][0] + sW[tid][1] + sW[tid][2] + sW[tid][3];
        ws[WS_PART_OFF + (size_t)blockIdx.x * 64 + tid] = t;  // deterministic
    }
}

__device__ __forceinline__ bool mask_at(const void* p, int idx, int mode) {
    if (mode == 0) return ((const int*)p)[idx] != 0;
    if (mode == 1) return ((const float*)p)[idx] != 0.f;
    return ((const unsigned char*)p)[idx] != 0;
}

// 1024 threads: 16-way parallel partial combine, wave 0 does the scalar tail
__global__ __launch_bounds__(1024) void k_final(const int* __restrict__ targets,
                                                const void* __restrict__ pmask,
                                                const void* __restrict__ nmask,
                                                const float* __restrict__ logits,
                                                const float* __restrict__ ws,
                                                float* __restrict__ out) {
    __shared__ float sSe[1024];
    int tid = threadIdx.x;
    {
        int row = tid & 63, part = tid >> 6;   // 16 parts
        float se = 0.f;
        const float* __restrict__ P = ws + WS_PART_OFF;
        for (int b = part; b < NGB; b += 16) se += P[b * 64 + row];  // coalesced
        sSe[tid] = se;
    }
    __syncthreads();
    if (tid >= 64) return;

    int lane = tid;   // 0..63 == batch row
    float se = 0.f;
#pragma unroll
    for (int p = 0; p < 16; ++p) se += sSe[p * 64 + lane];

    // detect mask storage layout: int32 (0/1 words), float32 (0/1.0f), or uint8
    const unsigned int* pw = (const unsigned int*)pmask;
    int okInt = 1, okFlt = 1;
#pragma unroll
    for (int i = 0; i < 16; ++i) {
        unsigned int wv = pw[lane * 16 + i];
        okInt = okInt && (wv <= 1u);
        okFlt = okFlt && (wv == 0u || wv == 0x3f800000u);
    }
    int mode = __all(okInt) ? 0 : (__all(okFlt) ? 1 : 2);

    float lse = logf(se);
    int tgt = targets[lane];
    float nll = lse - logits[(size_t)lane * CC + tgt];

    const float* G = ws + WS_GRAM_OFF;
    float rinv = rsqrtf(G[lane * 64 + lane]);

    float minp = INFINITY, maxthd = -INFINITY;
    for (int j = 0; j < 64; ++j) {
        float rj = __shfl(rinv, j, 64);
        float sim = G[lane * 64 + j] * rinv * rj;
        sim = fminf(1.f, fmaxf(-1.f, sim));
        if (j != lane) {
            bool pm = mask_at(pmask, lane * 64 + j, mode);
            float ps = pm ? sim : 2.0f;
            minp = fminf(minp, ps);
            maxthd = fmaxf(maxthd, pm ? sim : -2.0f);   // sentinel 2.0 -> -2.0
        }
    }
    float n_thrd = minp - NMARG;
    float p_thrd = maxthd - PMARG;

    float hps = 0.f, hns = 0.f, hpc = 0.f, hnc = 0.f;
    for (int j = 0; j < 64; ++j) {
        float rj = __shfl(rinv, j, 64);
        float sim = G[lane * 64 + j] * rinv * rj;
        sim = fminf(1.f, fmaxf(-1.f, sim));
        if (j != lane) {
            bool pm = mask_at(pmask, lane * 64 + j, mode);
            bool nm = mask_at(nmask, lane * 64 + j, mode);
            float ps = pm ? sim : 2.0f;
            float ns = nm ? sim : 2.0f;
            if (ps < p_thrd) { hps += log1pf(expf(-ps)); hpc += 1.f; }
            if (ns < n_thrd) { hns += log1pf(expf(-ns)); hnc += 1.f; }
        }
    }

    float snll = wredf(nll);
    float shps = wredf(hps);
    float shns = wredf(hns);
    float shpc = wredf(hpc);
    float shnc = wredf(hnc);
    if (lane == 0) {
        float bu = snll * (1.f / 64.f);
        float hp = shpc > 0.f ? shps / shpc : 0.f;
        float hn = shnc > 0.f ? shns / shnc : 0.f;
        out[0] = bu + hp + hn;
    }
}

extern "C" void kernel_launch(void* const* d_in, const int* in_sizes, int n_in,
                              void* d_out, int out_size, void* d_ws, size_t ws_size,
                              hipStream_t stream) {
    const float* inputs = (const float*)d_in[0];
    const int* targets  = (const int*)d_in[1];
    const void* pmask   = d_in[2];
    const void* nmask   = d_in[3];
    const float* V      = (const float*)d_in[4];
    float* out = (float*)d_out;      // out[0] = loss
    float* logits = out + 1;         // out[1..] = logits [64][100000] row-major
    float* ws = (float*)d_ws;        // A-pack | Gram | exp partials (~450KB)

    hipLaunchKernelGGL(k_prep, dim3(2), dim3(256), 0, stream, inputs, ws);
    hipLaunchKernelGGL(k_gemm, dim3(NGB), dim3(512), 0, stream,
                       V, ws, logits, ws);
    hipLaunchKernelGGL(k_final, dim3(1), dim3(1024), 0, stream,
                       targets, pmask, nmask, logits, ws, out);
}

// Round 7
// 118.817 us; speedup vs baseline: 2.0293x; 1.1867x over previous
//
#include <hip/hip_runtime.h>
#include <math.h>

#define BB 64
#define FF 256
#define CC 100000
#define PMARG 0.2f
#define NMARG 0.3f
#define CGB 64                   // cols per gemm block
#define NGB 1563                 // ceil(CC/CGB)
#define WS_A_OFF 0               // ws: [0..8191] A bf16 fragment pack (32KB)
#define WS_GRAM_OFF 8192         // [8192..12287] Gram 64x64 f32
#define WS_PART_OFF 12288        // [12288..112319] exp partials NGB*64
#define WS_SE_OFF 112320         // [112320..112383] row exp-sums

typedef __attribute__((ext_vector_type(8))) short short8;   // 8 bf16 = 4 VGPR
typedef __attribute__((ext_vector_type(4))) float f32x4;

__device__ __forceinline__ float wredf(float v) {
#pragma unroll
    for (int s = 1; s < 64; s <<= 1) v += __shfl_xor(v, s, 64);
    return v;
}

// f32 -> bf16 round-to-nearest-even
__device__ __forceinline__ short f2bf(float f) {
    unsigned u = __float_as_uint(f);
    unsigned r = (u + 0x7fffu + ((u >> 16) & 1u)) >> 16;
    return (short)r;
}
__device__ __forceinline__ short8 pack8(float4 a, float4 b) {
    short8 o;
    o[0] = f2bf(a.x); o[1] = f2bf(a.y); o[2] = f2bf(a.z); o[3] = f2bf(a.w);
    o[4] = f2bf(b.x); o[5] = f2bf(b.y); o[6] = f2bf(b.z); o[7] = f2bf(b.w);
    return o;
}

// block 0: pack A into bf16 MFMA fragments (lane-ordered, coalesced for gemm)
// block 1: Gram matrix G = inputs @ inputs.T (f32, accuracy-critical)
__global__ __launch_bounds__(256) void k_prep(const float* __restrict__ in,
                                              float* __restrict__ ws) {
    int tid = threadIdx.x;
    const float4* __restrict__ in4 = (const float4*)in;
    if (blockIdx.x == 0) {
        short8* __restrict__ wsa = (short8*)(ws + WS_A_OFF);
#pragma unroll
        for (int i = 0; i < 8; ++i) {
            int idx = i * 256 + tid;          // (mt*8+ks)*64 + lane
            int lane = idx & 63;
            int ks = (idx >> 6) & 7;
            int mt = idx >> 9;
            int row = mt * 16 + (lane & 15);
            int kq = ks * 8 + (lane >> 4) * 2;   // float4 index
            wsa[idx] = pack8(in4[row * 64 + kq], in4[row * 64 + kq + 1]);
        }
    } else {
        int r0 = (tid >> 4) << 2;
        int c0 = (tid & 15) << 2;
        float gacc[4][4];
#pragma unroll
        for (int r = 0; r < 4; ++r)
#pragma unroll
            for (int c = 0; c < 4; ++c) gacc[r][c] = 0.f;
        for (int kq = 0; kq < 64; ++kq) {
            float4 a[4], b[4];
#pragma unroll
            for (int r = 0; r < 4; ++r) a[r] = in4[(r0 + r) * 64 + kq];
#pragma unroll
            for (int c = 0; c < 4; ++c) b[c] = in4[(c0 + c) * 64 + kq];
#pragma unroll
            for (int r = 0; r < 4; ++r)
#pragma unroll
                for (int c = 0; c < 4; ++c)
                    gacc[r][c] += a[r].x * b[c].x + a[r].y * b[c].y +
                                  a[r].z * b[c].z + a[r].w * b[c].w;
        }
        float* G = ws + WS_GRAM_OFF;
#pragma unroll
        for (int r = 0; r < 4; ++r)
#pragma unroll
            for (int c = 0; c < 4; ++c)
                G[(r0 + r) * 64 + (c0 + c)] = gacc[r][c];
    }
}

// Wave-autonomous GEMM: 8 waves/block, wave = 16 cols x 32 rows.
__global__ __launch_bounds__(512, 3) void k_gemm(const float* __restrict__ V,
                                                 const float* __restrict__ ws_in,
                                                 float* __restrict__ logits,
                                                 float* __restrict__ ws) {
    __shared__ float sW[64][4];
    int tid = threadIdx.x;
    int lane = tid & 63, w = tid >> 6;
    int cg = w & 3, h = w >> 2;          // col-group 0..3, row-half 0..1
    int g = lane >> 4, c4 = lane & 15;
    int col = blockIdx.x * CGB + cg * 16 + c4;
    bool cv = col < CC;
    int ccol = cv ? col : CC - 1;

    // ---- issue all 16 B loads (f32, 32B per lane per ks) ----
    const float4* __restrict__ vp = (const float4*)(V + (size_t)ccol * FF);
    float4 vb[8][2];
#pragma unroll
    for (int ks = 0; ks < 8; ++ks) {
        vb[ks][0] = vp[ks * 8 + g * 2];
        vb[ks][1] = vp[ks * 8 + g * 2 + 1];
    }

    // ---- A fragments: pre-packed, coalesced, L2-hot ----
    const short8* __restrict__ wsa = (const short8*)(ws_in + WS_A_OFF);
    const short8* __restrict__ ap0 = wsa + (h * 2 + 0) * 512 + lane;
    const short8* __restrict__ ap1 = wsa + (h * 2 + 1) * 512 + lane;

    f32x4 acc0 = {0.f, 0.f, 0.f, 0.f};
    f32x4 acc1 = {0.f, 0.f, 0.f, 0.f};
#pragma unroll
    for (int ks = 0; ks < 8; ++ks) {
        short8 a0 = ap0[ks * 64];
        short8 a1 = ap1[ks * 64];
        short8 bf = pack8(vb[ks][0], vb[ks][1]);
        acc0 = __builtin_amdgcn_mfma_f32_16x16x32_bf16(a0, bf, acc0, 0, 0, 0);
        acc1 = __builtin_amdgcn_mfma_f32_16x16x32_bf16(a1, bf, acc1, 0, 0, 0);
    }

    // ---- epilogue: stores + fused exp partials ----
#pragma unroll
    for (int r = 0; r < 4; ++r) {
        int row0 = (h * 2) * 16 + g * 4 + r;
        int row1 = (h * 2 + 1) * 16 + g * 4 + r;
        float lg0 = acc0[r], lg1 = acc1[r];
        if (cv) {
            logits[(size_t)row0 * CC + col] = lg0;
            logits[(size_t)row1 * CC + col] = lg1;
        }
        float e0 = cv ? expf(lg0) : 0.f;
        float e1 = cv ? expf(lg1) : 0.f;
        e0 += __shfl_xor(e0, 1, 64); e0 += __shfl_xor(e0, 2, 64);
        e0 += __shfl_xor(e0, 4, 64); e0 += __shfl_xor(e0, 8, 64);
        e1 += __shfl_xor(e1, 1, 64); e1 += __shfl_xor(e1, 2, 64);
        e1 += __shfl_xor(e1, 4, 64); e1 += __shfl_xor(e1, 8, 64);
        if (c4 == 0) {
            sW[row0][cg] = e0;
            sW[row1][cg] = e1;
        }
    }
    __syncthreads();
    if (tid < 64) {
        float t = sW[tid][0] + sW[tid][1] + sW[tid][2] + sW[tid][3];
        ws[WS_PART_OFF + (size_t)blockIdx.x * 64 + tid] = t;  // deterministic
    }
}

// 64 blocks (one per batch row): parallel deterministic reduce of exp partials
__global__ __launch_bounds__(256) void k_comb(const float* __restrict__ ws_in,
                                              float* __restrict__ ws) {
    __shared__ float sS[256];
    int row = blockIdx.x;
    int tid = threadIdx.x;
    const float* __restrict__ P = ws_in + WS_PART_OFF;
    float s = 0.f;
    for (int b = tid; b < NGB; b += 256) s += P[(size_t)b * 64 + row];
    sS[tid] = s;
    __syncthreads();
    if (tid < 128) sS[tid] += sS[tid + 128];
    __syncthreads();
    if (tid < 64) {
        float v = sS[tid] + sS[tid + 64];
        v = wredf(v);
        if (tid == 0) ws[WS_SE_OFF + row] = v;
    }
}

__device__ __forceinline__ bool mask_at(const void* p, int idx, int mode) {
    if (mode == 0) return ((const int*)p)[idx] != 0;
    if (mode == 1) return ((const float*)p)[idx] != 0.f;
    return ((const unsigned char*)p)[idx] != 0;
}

// 1 block x 256 threads: stage G + masks into LDS, wave 0 runs the tail
__global__ __launch_bounds__(256) void k_final(const int* __restrict__ targets,
                                               const void* __restrict__ pmask,
                                               const void* __restrict__ nmask,
                                               const float* __restrict__ logits,
                                               const float* __restrict__ ws,
                                               float* __restrict__ out) {
    __shared__ float sG[4096];        // Gram 64x64
    __shared__ char sPM[16384];
    __shared__ char sNM[16384];
    __shared__ int sMode;
    int tid = threadIdx.x;

    // early-issue the per-row scalars so latency hides under staging
    float myLogit = 0.f, mySe = 0.f;
    if (tid < 64) {
        int tgt = targets[tid];
        myLogit = logits[(size_t)tid * CC + tgt];
        mySe = ws[WS_SE_OFF + tid];
    }

    // stage G coalesced
    {
        const float4* __restrict__ G4 = (const float4*)(ws + WS_GRAM_OFF);
        float4* sG4 = (float4*)sG;
#pragma unroll
        for (int i = 0; i < 4; ++i) sG4[tid + i * 256] = G4[tid + i * 256];
    }

    // mode detect on wave 0 (identical semantics to prior rounds)
    if (tid < 64) {
        const unsigned int* pw = (const unsigned int*)pmask;
        int okInt = 1, okFlt = 1;
#pragma unroll
        for (int i = 0; i < 16; ++i) {
            unsigned int wv = pw[tid * 16 + i];
            okInt = okInt && (wv <= 1u);
            okFlt = okFlt && (wv == 0u || wv == 0x3f800000u);
        }
        int mode = __all(okInt) ? 0 : (__all(okFlt) ? 1 : 2);
        if (tid == 0) sMode = mode;
    }
    __syncthreads();
    int mode = sMode;
    int mq = (mode == 2) ? 256 : 1024;    // float4 count: 4KB or 16KB per mask
    for (int i = tid; i < mq; i += 256) {
        ((float4*)sPM)[i] = ((const float4*)pmask)[i];
        ((float4*)sNM)[i] = ((const float4*)nmask)[i];
    }
    __syncthreads();
    if (tid >= 64) return;

    int lane = tid;   // 0..63 == batch row
    float lse = logf(mySe);
    float nll = lse - myLogit;

    float rinv = rsqrtf(sG[lane * 64 + lane]);

    float minp = INFINITY, maxthd = -INFINITY;
    for (int j = 0; j < 64; ++j) {
        float rj = __shfl(rinv, j, 64);
        float sim = sG[lane * 64 + j] * rinv * rj;
        sim = fminf(1.f, fmaxf(-1.f, sim));
        if (j != lane) {
            bool pm = mask_at(sPM, lane * 64 + j, mode);
            float ps = pm ? sim : 2.0f;
            minp = fminf(minp, ps);
            maxthd = fmaxf(maxthd, pm ? sim : -2.0f);   // sentinel 2.0 -> -2.0
        }
    }
    float n_thrd = minp - NMARG;
    float p_thrd = maxthd - PMARG;

    float hps = 0.f, hns = 0.f, hpc = 0.f, hnc = 0.f;
    for (int j = 0; j < 64; ++j) {
        float rj = __shfl(rinv, j, 64);
        float sim = sG[lane * 64 + j] * rinv * rj;
        sim = fminf(1.f, fmaxf(-1.f, sim));
        if (j != lane) {
            bool pm = mask_at(sPM, lane * 64 + j, mode);
            bool nm = mask_at(sNM, lane * 64 + j, mode);
            float ps = pm ? sim : 2.0f;
            float ns = nm ? sim : 2.0f;
            if (ps < p_thrd) { hps += log1pf(expf(-ps)); hpc += 1.f; }
            if (ns < n_thrd) { hns += log1pf(expf(-ns)); hnc += 1.f; }
        }
    }

    float snll = wredf(nll);
    float shps = wredf(hps);
    float shns = wredf(hns);
    float shpc = wredf(hpc);
    float shnc = wredf(hnc);
    if (lane == 0) {
        float bu = snll * (1.f / 64.f);
        float hp = shpc > 0.f ? shps / shpc : 0.f;
        float hn = shnc > 0.f ? shns / shnc : 0.f;
        out[0] = bu + hp + hn;
    }
}

extern "C" void kernel_launch(void* const* d_in, const int* in_sizes, int n_in,
                              void* d_out, int out_size, void* d_ws, size_t ws_size,
                              hipStream_t stream) {
    const float* inputs = (const float*)d_in[0];
    const int* targets  = (const int*)d_in[1];
    const void* pmask   = d_in[2];
    const void* nmask   = d_in[3];
    const float* V      = (const float*)d_in[4];
    float* out = (float*)d_out;      // out[0] = loss
    float* logits = out + 1;         // out[1..] = logits [64][100000] row-major
    float* ws = (float*)d_ws;        // A-pack | Gram | partials | row-sums

    hipLaunchKernelGGL(k_prep, dim3(2), dim3(256), 0, stream, inputs, ws);
    hipLaunchKernelGGL(k_gemm, dim3(NGB), dim3(512), 0, stream,
                       V, ws, logits, ws);
    hipLaunchKernelGGL(k_comb, dim3(64), dim3(256), 0, stream, ws, ws);
    hipLaunchKernelGGL(k_final, dim3(1), dim3(256), 0, stream,
                       targets, pmask, nmask, logits, ws, out);
}

// Round 8
// 112.566 us; speedup vs baseline: 2.1420x; 1.0555x over previous
//
#include <hip/hip_runtime.h>
#include <math.h>

#define BB 64
#define FF 256
#define CC 100000
#define PMARG 0.2f
#define NMARG 0.3f
#define CGB 64                   // cols per gemm block
#define NGB 1563                 // ceil(CC/CGB)
#define WS_A_OFF 0               // ws: [0..8191] A bf16 fragment pack (32KB)
#define WS_GRAM_OFF 8192         // [8192..12287] Gram 64x64 f32
#define WS_PART_OFF 12288        // [12288..112319] exp partials NGB*64
#define WS_SE_OFF 112320         // [112320..112383] row exp-sums

typedef __attribute__((ext_vector_type(8))) short short8;   // 8 bf16 = 4 VGPR
typedef __attribute__((ext_vector_type(4))) short sh4;      // 4 bf16 = 8B
typedef __attribute__((ext_vector_type(4))) float f32x4;

__device__ __forceinline__ float wredf(float v) {
#pragma unroll
    for (int s = 1; s < 64; s <<= 1) v += __shfl_xor(v, s, 64);
    return v;
}

// f32 -> bf16 round-to-nearest-even
__device__ __forceinline__ short f2bf(float f) {
    unsigned u = __float_as_uint(f);
    unsigned r = (u + 0x7fffu + ((u >> 16) & 1u)) >> 16;
    return (short)r;
}
__device__ __forceinline__ short8 pack8(float4 a, float4 b) {
    short8 o;
    o[0] = f2bf(a.x); o[1] = f2bf(a.y); o[2] = f2bf(a.z); o[3] = f2bf(a.w);
    o[4] = f2bf(b.x); o[5] = f2bf(b.y); o[6] = f2bf(b.z); o[7] = f2bf(b.w);
    return o;
}

// block 0: pack A into bf16 MFMA fragments; block 1: Gram via LDS staging
__global__ __launch_bounds__(256) void k_prep(const float* __restrict__ in,
                                              float* __restrict__ ws) {
    int tid = threadIdx.x;
    const float4* __restrict__ in4 = (const float4*)in;
    if (blockIdx.x == 0) {
        short8* __restrict__ wsa = (short8*)(ws + WS_A_OFF);
#pragma unroll
        for (int i = 0; i < 8; ++i) {
            int idx = i * 256 + tid;          // (mt*8+ks)*64 + lane
            int lane = idx & 63;
            int ks = (idx >> 6) & 7;
            int mt = idx >> 9;
            int row = mt * 16 + (lane & 15);
            int kq = ks * 8 + (lane >> 4) * 2;   // float4 index
            wsa[idx] = pack8(in4[row * 64 + kq], in4[row * 64 + kq + 1]);
        }
    } else {
        __shared__ float4 sIn[64 * 64];       // inputs, 64KB
#pragma unroll
        for (int i = 0; i < 16; ++i) sIn[i * 256 + tid] = in4[i * 256 + tid];
        __syncthreads();
        int r0 = (tid >> 4) << 2;
        int c0 = (tid & 15) << 2;
        float gacc[4][4];
#pragma unroll
        for (int r = 0; r < 4; ++r)
#pragma unroll
            for (int c = 0; c < 4; ++c) gacc[r][c] = 0.f;
        for (int kq = 0; kq < 64; ++kq) {
            float4 a[4], b[4];
#pragma unroll
            for (int r = 0; r < 4; ++r) a[r] = sIn[(r0 + r) * 64 + kq];
#pragma unroll
            for (int c = 0; c < 4; ++c) b[c] = sIn[(c0 + c) * 64 + kq];
#pragma unroll
            for (int r = 0; r < 4; ++r)
#pragma unroll
                for (int c = 0; c < 4; ++c)
                    gacc[r][c] += a[r].x * b[c].x + a[r].y * b[c].y +
                                  a[r].z * b[c].z + a[r].w * b[c].w;
        }
        float* G = ws + WS_GRAM_OFF;
#pragma unroll
        for (int r = 0; r < 4; ++r)
#pragma unroll
            for (int c = 0; c < 4; ++c)
                G[(r0 + r) * 64 + (c0 + c)] = gacc[r][c];
    }
}

// GEMM: 256 threads, 64 cols/block. V staged coalesced into 32KB LDS (bf16,
// XOR-swizzled); A streamed from pre-packed fragment buffer (L1/L2-hot).
// Wave w computes cols [w*16, w*16+16) x all 64 rows (4 MFMA m-tiles).
__global__ __launch_bounds__(256) void k_gemm(const float* __restrict__ V,
                                              const float* __restrict__ ws_in,
                                              float* __restrict__ logits,
                                              float* __restrict__ ws) {
    __shared__ char sB[CGB * 512];        // [64 rows][256 k] bf16, swizzled
    __shared__ float sW[64][4];
    int tid = threadIdx.x;
    int col0 = blockIdx.x * CGB;

    // ---- stage V tile: each wave-load = one whole 1KB V row (coalesced) ----
    const float4* __restrict__ V4 = (const float4*)V;
#pragma unroll
    for (int i = 0; i < 16; ++i) {
        int flat = i * 256 + tid;
        int row = flat >> 6;              // 0..63
        int c8 = flat & 63;               // float4 index in the row
        int vr = col0 + row;
        if (vr >= CC) vr = CC - 1;        // pad rows duplicate last (guarded)
        float4 gv = V4[(size_t)vr * 64 + c8];
        sh4 b;
        b[0] = f2bf(gv.x); b[1] = f2bf(gv.y); b[2] = f2bf(gv.z); b[3] = f2bf(gv.w);
        int off = (row * 512 + c8 * 8) ^ ((row & 7) << 4);
        *(sh4*)(sB + off) = b;
    }

    int lane = tid & 63, w = tid >> 6;
    int g = lane >> 4, c4 = lane & 15;
    int col = col0 + w * 16 + c4;
    bool cv = col < CC;
    int rb = w * 16 + c4;                 // B row in tile
    __syncthreads();

    const short8* __restrict__ wsa = (const short8*)(ws_in + WS_A_OFF);
    f32x4 acc[4];
#pragma unroll
    for (int mt = 0; mt < 4; ++mt) acc[mt] = (f32x4){0.f, 0.f, 0.f, 0.f};

#pragma unroll
    for (int ks = 0; ks < 8; ++ks) {
        int off = (rb * 512 + ks * 64 + g * 16) ^ ((rb & 7) << 4);
        short8 bf = *(const short8*)(sB + off);
#pragma unroll
        for (int mt = 0; mt < 4; ++mt) {
            short8 a = wsa[(mt * 8 + ks) * 64 + lane];   // coalesced, L1-hot
            acc[mt] = __builtin_amdgcn_mfma_f32_16x16x32_bf16(a, bf, acc[mt], 0, 0, 0);
        }
    }

    // ---- epilogue: stores + fused exp row-sum partials ----
#pragma unroll
    for (int mt = 0; mt < 4; ++mt)
#pragma unroll
        for (int r = 0; r < 4; ++r) {
            int row = mt * 16 + g * 4 + r;
            float lg = acc[mt][r];
            if (cv) logits[(size_t)row * CC + col] = lg;
            float e = cv ? expf(lg) : 0.f;
            e += __shfl_xor(e, 1, 64); e += __shfl_xor(e, 2, 64);
            e += __shfl_xor(e, 4, 64); e += __shfl_xor(e, 8, 64);
            if (c4 == 0) sW[row][w] = e;
        }
    __syncthreads();
    if (tid < 64) {
        float t = sW[tid][0] + sW[tid][1] + sW[tid][2] + sW[tid][3];
        ws[WS_PART_OFF + (size_t)blockIdx.x * 64 + tid] = t;  // deterministic
    }
}

// 64 blocks (one per batch row): parallel deterministic reduce of exp partials
__global__ __launch_bounds__(256) void k_comb(const float* __restrict__ ws_in,
                                              float* __restrict__ ws) {
    __shared__ float sS[256];
    int row = blockIdx.x;
    int tid = threadIdx.x;
    const float* __restrict__ P = ws_in + WS_PART_OFF;
    float s = 0.f;
    for (int b = tid; b < NGB; b += 256) s += P[(size_t)b * 64 + row];
    sS[tid] = s;
    __syncthreads();
    if (tid < 128) sS[tid] += sS[tid + 128];
    __syncthreads();
    if (tid < 64) {
        float v = sS[tid] + sS[tid + 64];
        v = wredf(v);
        if (tid == 0) ws[WS_SE_OFF + row] = v;
    }
}

__device__ __forceinline__ bool mask_at(const void* p, int idx, int mode) {
    if (mode == 0) return ((const int*)p)[idx] != 0;
    if (mode == 1) return ((const float*)p)[idx] != 0.f;
    return ((const unsigned char*)p)[idx] != 0;
}

// 1 block x 256 threads: stage G + masks into LDS, wave 0 runs the tail
__global__ __launch_bounds__(256) void k_final(const int* __restrict__ targets,
                                               const void* __restrict__ pmask,
                                               const void* __restrict__ nmask,
                                               const float* __restrict__ logits,
                                               const float* __restrict__ ws,
                                               float* __restrict__ out) {
    __shared__ float sG[4096];        // Gram 64x64
    __shared__ char sPM[16384];
    __shared__ char sNM[16384];
    __shared__ int sMode;
    int tid = threadIdx.x;

    // early-issue the per-row scalars so latency hides under staging
    float myLogit = 0.f, mySe = 0.f;
    if (tid < 64) {
        int tgt = targets[tid];
        myLogit = logits[(size_t)tid * CC + tgt];
        mySe = ws[WS_SE_OFF + tid];
    }

    // stage G coalesced
    {
        const float4* __restrict__ G4 = (const float4*)(ws + WS_GRAM_OFF);
        float4* sG4 = (float4*)sG;
#pragma unroll
        for (int i = 0; i < 4; ++i) sG4[tid + i * 256] = G4[tid + i * 256];
    }

    // mode detect on wave 0 (identical semantics to prior rounds)
    if (tid < 64) {
        const unsigned int* pw = (const unsigned int*)pmask;
        int okInt = 1, okFlt = 1;
#pragma unroll
        for (int i = 0; i < 16; ++i) {
            unsigned int wv = pw[tid * 16 + i];
            okInt = okInt && (wv <= 1u);
            okFlt = okFlt && (wv == 0u || wv == 0x3f800000u);
        }
        int mode = __all(okInt) ? 0 : (__all(okFlt) ? 1 : 2);
        if (tid == 0) sMode = mode;
    }
    __syncthreads();
    int mode = sMode;
    int mq = (mode == 2) ? 256 : 1024;    // float4 count: 4KB or 16KB per mask
    for (int i = tid; i < mq; i += 256) {
        ((float4*)sPM)[i] = ((const float4*)pmask)[i];
        ((float4*)sNM)[i] = ((const float4*)nmask)[i];
    }
    __syncthreads();
    if (tid >= 64) return;

    int lane = tid;   // 0..63 == batch row
    float lse = logf(mySe);
    float nll = lse - myLogit;

    float rinv = rsqrtf(sG[lane * 64 + lane]);

    float minp = INFINITY, maxthd = -INFINITY;
    for (int j = 0; j < 64; ++j) {
        float rj = __shfl(rinv, j, 64);
        float sim = sG[lane * 64 + j] * rinv * rj;
        sim = fminf(1.f, fmaxf(-1.f, sim));
        if (j != lane) {
            bool pm = mask_at(sPM, lane * 64 + j, mode);
            float ps = pm ? sim : 2.0f;
            minp = fminf(minp, ps);
            maxthd = fmaxf(maxthd, pm ? sim : -2.0f);   // sentinel 2.0 -> -2.0
        }
    }
    float n_thrd = minp - NMARG;
    float p_thrd = maxthd - PMARG;

    float hps = 0.f, hns = 0.f, hpc = 0.f, hnc = 0.f;
    for (int j = 0; j < 64; ++j) {
        float rj = __shfl(rinv, j, 64);
        float sim = sG[lane * 64 + j] * rinv * rj;
        sim = fminf(1.f, fmaxf(-1.f, sim));
        if (j != lane) {
            bool pm = mask_at(sPM, lane * 64 + j, mode);
            bool nm = mask_at(sNM, lane * 64 + j, mode);
            float ps = pm ? sim : 2.0f;
            float ns = nm ? sim : 2.0f;
            if (ps < p_thrd) { hps += log1pf(expf(-ps)); hpc += 1.f; }
            if (ns < n_thrd) { hns += log1pf(expf(-ns)); hnc += 1.f; }
        }
    }

    float snll = wredf(nll);
    float shps = wredf(hps);
    float shns = wredf(hns);
    float shpc = wredf(hpc);
    float shnc = wredf(hnc);
    if (lane == 0) {
        float bu = snll * (1.f / 64.f);
        float hp = shpc > 0.f ? shps / shpc : 0.f;
        float hn = shnc > 0.f ? shns / shnc : 0.f;
        out[0] = bu + hp + hn;
    }
}

extern "C" void kernel_launch(void* const* d_in, const int* in_sizes, int n_in,
                              void* d_out, int out_size, void* d_ws, size_t ws_size,
                              hipStream_t stream) {
    const float* inputs = (const float*)d_in[0];
    const int* targets  = (const int*)d_in[1];
    const void* pmask   = d_in[2];
    const void* nmask   = d_in[3];
    const float* V      = (const float*)d_in[4];
    float* out = (float*)d_out;      // out[0] = loss
    float* logits = out + 1;         // out[1..] = logits [64][100000] row-major
    float* ws = (float*)d_ws;        // A-pack | Gram | partials | row-sums

    hipLaunchKernelGGL(k_prep, dim3(2), dim3(256), 0, stream, inputs, ws);
    hipLaunchKernelGGL(k_gemm, dim3(NGB), dim3(256), 0, stream,
                       V, ws, logits, ws);
    hipLaunchKernelGGL(k_comb, dim3(64), dim3(256), 0, stream, ws, ws);
    hipLaunchKernelGGL(k_final, dim3(1), dim3(256), 0, stream,
                       targets, pmask, nmask, logits, ws, out);
}

// Round 9
// 109.627 us; speedup vs baseline: 2.1994x; 1.0268x over previous
//
#include <hip/hip_runtime.h>
#include <math.h>

#define BB 64
#define FF 256
#define CC 100000
#define PMARG 0.2f
#define NMARG 0.3f
#define CGB 64                   // cols per gemm block
#define NGB 1563                 // ceil(CC/CGB)
#define WS_A_OFF 0               // ws: [0..8191] A bf16 fragment pack (32KB)
#define WS_GRAM_OFF 8192         // [8192..12287] Gram 64x64 f32
#define WS_PART_OFF 12288        // [12288..112319] exp partials NGB*64
#define WS_SE_OFF 112320         // [112320..112383] row exp-sums

typedef __attribute__((ext_vector_type(8))) short short8;   // 8 bf16 = 4 VGPR
typedef __attribute__((ext_vector_type(4))) float f32x4;

__device__ __forceinline__ float wredf(float v) {
#pragma unroll
    for (int s = 1; s < 64; s <<= 1) v += __shfl_xor(v, s, 64);
    return v;
}

// f32 -> bf16 round-to-nearest-even
__device__ __forceinline__ short f2bf(float f) {
    unsigned u = __float_as_uint(f);
    unsigned r = (u + 0x7fffu + ((u >> 16) & 1u)) >> 16;
    return (short)r;
}
__device__ __forceinline__ short8 pack8(float4 a, float4 b) {
    short8 o;
    o[0] = f2bf(a.x); o[1] = f2bf(a.y); o[2] = f2bf(a.z); o[3] = f2bf(a.w);
    o[4] = f2bf(b.x); o[5] = f2bf(b.y); o[6] = f2bf(b.z); o[7] = f2bf(b.w);
    return o;
}

// block 0: pack A into bf16 MFMA fragments; block 1: Gram via LDS staging
__global__ __launch_bounds__(256) void k_prep(const float* __restrict__ in,
                                              float* __restrict__ ws) {
    int tid = threadIdx.x;
    const float4* __restrict__ in4 = (const float4*)in;
    if (blockIdx.x == 0) {
        short8* __restrict__ wsa = (short8*)(ws + WS_A_OFF);
#pragma unroll
        for (int i = 0; i < 8; ++i) {
            int idx = i * 256 + tid;          // (mt*8+ks)*64 + lane
            int lane = idx & 63;
            int ks = (idx >> 6) & 7;
            int mt = idx >> 9;
            int row = mt * 16 + (lane & 15);
            int kq = ks * 8 + (lane >> 4) * 2;   // float4 index
            wsa[idx] = pack8(in4[row * 64 + kq], in4[row * 64 + kq + 1]);
        }
    } else {
        __shared__ float4 sIn[64 * 64];       // inputs, 64KB
#pragma unroll
        for (int i = 0; i < 16; ++i) sIn[i * 256 + tid] = in4[i * 256 + tid];
        __syncthreads();
        int r0 = (tid >> 4) << 2;
        int c0 = (tid & 15) << 2;
        float gacc[4][4];
#pragma unroll
        for (int r = 0; r < 4; ++r)
#pragma unroll
            for (int c = 0; c < 4; ++c) gacc[r][c] = 0.f;
        for (int kq = 0; kq < 64; ++kq) {
            float4 a[4], b[4];
#pragma unroll
            for (int r = 0; r < 4; ++r) a[r] = sIn[(r0 + r) * 64 + kq];
#pragma unroll
            for (int c = 0; c < 4; ++c) b[c] = sIn[(c0 + c) * 64 + kq];
#pragma unroll
            for (int r = 0; r < 4; ++r)
#pragma unroll
                for (int c = 0; c < 4; ++c)
                    gacc[r][c] += a[r].x * b[c].x + a[r].y * b[c].y +
                                  a[r].z * b[c].z + a[r].w * b[c].w;
        }
        float* G = ws + WS_GRAM_OFF;
#pragma unroll
        for (int r = 0; r < 4; ++r)
#pragma unroll
            for (int c = 0; c < 4; ++c)
                G[(r0 + r) * 64 + (c0 + c)] = gacc[r][c];
    }
}

// GEMM: 512 threads (8 waves), 64 cols/block. V staged f32 direct-to-LDS via
// global_load_lds (async, zero VGPR), source-XOR-swizzled to kill the 16-way
// row-stride bank conflict; bf16 conversion on the read side. A streamed from
// the pre-packed fragment buffer (L1-hot). Wave w: col-group w&3, row-half w>>2.
__global__ __launch_bounds__(512, 4) void k_gemm(const float* __restrict__ V,
                                                 const float* __restrict__ ws_in,
                                                 float* __restrict__ logits,
                                                 float* __restrict__ ws) {
    __shared__ float4 sB4[CGB * 64];      // [64 rows][64 float4] = 64KB, swizzled
    __shared__ float sW[64][4];
    int tid = threadIdx.x;
    int lane = tid & 63, w = tid >> 6;
    int col0 = blockIdx.x * CGB;

    // ---- async stage: wave w loads rows {i*8+w}; LDS base wave-uniform,
    //      HW writes base + lane*16; global src per-lane with XOR swizzle ----
#pragma unroll
    for (int i = 0; i < 8; ++i) {
        int r = i * 8 + w;
        int vr = col0 + r;
        if (vr >= CC) vr = CC - 1;        // pad rows duplicate last (guarded)
        const float4* src = (const float4*)V + (size_t)vr * 64 + (lane ^ (r & 7));
        char* dst = (char*)sB4 + r * 1024;   // wave-uniform
        __builtin_amdgcn_global_load_lds(
            (const __attribute__((address_space(1))) void*)src,
            (__attribute__((address_space(3))) void*)dst, 16, 0, 0);
    }

    int cg = w & 3, h = w >> 2;
    int g = lane >> 4, c4 = lane & 15;
    int col = col0 + cg * 16 + c4;
    bool cv = col < CC;
    int rb = cg * 16 + c4;                // B row in tile
    int m = rb & 7;                       // read-side XOR (matches source swizzle)

    const short8* __restrict__ wsa = (const short8*)(ws_in + WS_A_OFF);
    __syncthreads();                      // drains vmcnt + barrier

    f32x4 acc0 = {0.f, 0.f, 0.f, 0.f};
    f32x4 acc1 = {0.f, 0.f, 0.f, 0.f};
#pragma unroll
    for (int ks = 0; ks < 8; ++ks) {
        int u0 = ks * 8 + g * 2;
        float4 b0 = sB4[rb * 64 + (u0 ^ m)];
        float4 b1 = sB4[rb * 64 + ((u0 + 1) ^ m)];
        short8 bf = pack8(b0, b1);
        short8 a0 = wsa[((h * 2 + 0) * 8 + ks) * 64 + lane];   // L1-hot
        short8 a1 = wsa[((h * 2 + 1) * 8 + ks) * 64 + lane];
        acc0 = __builtin_amdgcn_mfma_f32_16x16x32_bf16(a0, bf, acc0, 0, 0, 0);
        acc1 = __builtin_amdgcn_mfma_f32_16x16x32_bf16(a1, bf, acc1, 0, 0, 0);
    }

    // ---- epilogue: stores + fused exp row-sum partials ----
#pragma unroll
    for (int q = 0; q < 2; ++q) {
        f32x4 a = q ? acc1 : acc0;
#pragma unroll
        for (int r = 0; r < 4; ++r) {
            int row = (h * 2 + q) * 16 + g * 4 + r;
            float lg = a[r];
            if (cv) logits[(size_t)row * CC + col] = lg;
            float e = cv ? expf(lg) : 0.f;
            e += __shfl_xor(e, 1, 64); e += __shfl_xor(e, 2, 64);
            e += __shfl_xor(e, 4, 64); e += __shfl_xor(e, 8, 64);
            if (c4 == 0) sW[row][cg] = e;
        }
    }
    __syncthreads();
    if (tid < 64) {
        float t = sW[tid][0] + sW[tid][1] + sW[tid][2] + sW[tid][3];
        ws[WS_PART_OFF + (size_t)blockIdx.x * 64 + tid] = t;  // deterministic
    }
}

// 64 blocks (one per batch row): parallel deterministic reduce of exp partials
__global__ __launch_bounds__(256) void k_comb(const float* __restrict__ ws_in,
                                              float* __restrict__ ws) {
    __shared__ float sS[256];
    int row = blockIdx.x;
    int tid = threadIdx.x;
    const float* __restrict__ P = ws_in + WS_PART_OFF;
    float s = 0.f;
    for (int b = tid; b < NGB; b += 256) s += P[(size_t)b * 64 + row];
    sS[tid] = s;
    __syncthreads();
    if (tid < 128) sS[tid] += sS[tid + 128];
    __syncthreads();
    if (tid < 64) {
        float v = sS[tid] + sS[tid + 64];
        v = wredf(v);
        if (tid == 0) ws[WS_SE_OFF + row] = v;
    }
}

__device__ __forceinline__ bool mask_at(const void* p, int idx, int mode) {
    if (mode == 0) return ((const int*)p)[idx] != 0;
    if (mode == 1) return ((const float*)p)[idx] != 0.f;
    return ((const unsigned char*)p)[idx] != 0;
}

// 1 block x 256 threads: stage G + masks into LDS, wave 0 runs the tail
__global__ __launch_bounds__(256) void k_final(const int* __restrict__ targets,
                                               const void* __restrict__ pmask,
                                               const void* __restrict__ nmask,
                                               const float* __restrict__ logits,
                                               const float* __restrict__ ws,
                                               float* __restrict__ out) {
    __shared__ float sG[4096];        // Gram 64x64
    __shared__ char sPM[16384];
    __shared__ char sNM[16384];
    __shared__ int sMode;
    int tid = threadIdx.x;

    // early-issue the per-row scalars so latency hides under staging
    float myLogit = 0.f, mySe = 0.f;
    if (tid < 64) {
        int tgt = targets[tid];
        myLogit = logits[(size_t)tid * CC + tgt];
        mySe = ws[WS_SE_OFF + tid];
    }

    // stage G coalesced
    {
        const float4* __restrict__ G4 = (const float4*)(ws + WS_GRAM_OFF);
        float4* sG4 = (float4*)sG;
#pragma unroll
        for (int i = 0; i < 4; ++i) sG4[tid + i * 256] = G4[tid + i * 256];
    }

    // mode detect on wave 0 (identical semantics to prior rounds)
    if (tid < 64) {
        const unsigned int* pw = (const unsigned int*)pmask;
        int okInt = 1, okFlt = 1;
#pragma unroll
        for (int i = 0; i < 16; ++i) {
            unsigned int wv = pw[tid * 16 + i];
            okInt = okInt && (wv <= 1u);
            okFlt = okFlt && (wv == 0u || wv == 0x3f800000u);
        }
        int mode = __all(okInt) ? 0 : (__all(okFlt) ? 1 : 2);
        if (tid == 0) sMode = mode;
    }
    __syncthreads();
    int mode = sMode;
    int mq = (mode == 2) ? 256 : 1024;    // float4 count: 4KB or 16KB per mask
    for (int i = tid; i < mq; i += 256) {
        ((float4*)sPM)[i] = ((const float4*)pmask)[i];
        ((float4*)sNM)[i] = ((const float4*)nmask)[i];
    }
    __syncthreads();
    if (tid >= 64) return;

    int lane = tid;   // 0..63 == batch row
    float lse = logf(mySe);
    float nll = lse - myLogit;

    float rinv = rsqrtf(sG[lane * 64 + lane]);

    float minp = INFINITY, maxthd = -INFINITY;
    for (int j = 0; j < 64; ++j) {
        float rj = __shfl(rinv, j, 64);
        float sim = sG[lane * 64 + j] * rinv * rj;
        sim = fminf(1.f, fmaxf(-1.f, sim));
        if (j != lane) {
            bool pm = mask_at(sPM, lane * 64 + j, mode);
            float ps = pm ? sim : 2.0f;
            minp = fminf(minp, ps);
            maxthd = fmaxf(maxthd, pm ? sim : -2.0f);   // sentinel 2.0 -> -2.0
        }
    }
    float n_thrd = minp - NMARG;
    float p_thrd = maxthd - PMARG;

    float hps = 0.f, hns = 0.f, hpc = 0.f, hnc = 0.f;
    for (int j = 0; j < 64; ++j) {
        float rj = __shfl(rinv, j, 64);
        float sim = sG[lane * 64 + j] * rinv * rj;
        sim = fminf(1.f, fmaxf(-1.f, sim));
        if (j != lane) {
            bool pm = mask_at(sPM, lane * 64 + j, mode);
            bool nm = mask_at(sNM, lane * 64 + j, mode);
            float ps = pm ? sim : 2.0f;
            float ns = nm ? sim : 2.0f;
            if (ps < p_thrd) { hps += log1pf(expf(-ps)); hpc += 1.f; }
            if (ns < n_thrd) { hns += log1pf(expf(-ns)); hnc += 1.f; }
        }
    }

    float snll = wredf(nll);
    float shps = wredf(hps);
    float shns = wredf(hns);
    float shpc = wredf(hpc);
    float shnc = wredf(hnc);
    if (lane == 0) {
        float bu = snll * (1.f / 64.f);
        float hp = shpc > 0.f ? shps / shpc : 0.f;
        float hn = shnc > 0.f ? shns / shnc : 0.f;
        out[0] = bu + hp + hn;
    }
}

extern "C" void kernel_launch(void* const* d_in, const int* in_sizes, int n_in,
                              void* d_out, int out_size, void* d_ws, size_t ws_size,
                              hipStream_t stream) {
    const float* inputs = (const float*)d_in[0];
    const int* targets  = (const int*)d_in[1];
    const void* pmask   = d_in[2];
    const void* nmask   = d_in[3];
    const float* V      = (const float*)d_in[4];
    float* out = (float*)d_out;      // out[0] = loss
    float* logits = out + 1;         // out[1..] = logits [64][100000] row-major
    float* ws = (float*)d_ws;        // A-pack | Gram | partials | row-sums

    hipLaunchKernelGGL(k_prep, dim3(2), dim3(256), 0, stream, inputs, ws);
    hipLaunchKernelGGL(k_gemm, dim3(NGB), dim3(512), 0, stream,
                       V, ws, logits, ws);
    hipLaunchKernelGGL(k_comb, dim3(64), dim3(256), 0, stream, ws, ws);
    hipLaunchKernelGGL(k_final, dim3(1), dim3(256), 0, stream,
                       targets, pmask, nmask, logits, ws, out);
}